// Round 12
// baseline (1839.688 us; speedup 1.0000x reference)
//
#include <hip/hip_runtime.h>

#define EPSN   1e-5f
#define NEGS   0.2f
#define NGRAPH 64
#define BSHIFT 9
#define NPBK   512            // nodes per bucket = 1<<BSHIFT
#define GCAP   96             // GAT LDS edge cap per node
#define NPART  64             // pooled partial copies (contention spreading)
#define PSTR   (NGRAPH * 32 + NGRAPH)   // 2112 floats per partial copy

typedef _Float16 half_t;
typedef _Float16 halfv8 __attribute__((ext_vector_type(8)));
typedef _Float16 halfv4 __attribute__((ext_vector_type(4)));
typedef _Float16 halfv2 __attribute__((ext_vector_type(2)));

__device__ __forceinline__ float lrelu(float e) { return e > 0.f ? e : NEGS * e; }

// ===================== binned CSR build =====================
__global__ void k_bin_count(const int* __restrict__ ed, int* __restrict__ bsize,
                            int E, int NB) {
    __shared__ int lcnt[1024];
    for (int i = threadIdx.x; i < NB; i += 256) lcnt[i] = 0;
    __syncthreads();
    int chunk = (E + gridDim.x - 1) / gridDim.x;
    int lo = blockIdx.x * chunk;
    int hi = min(E, lo + chunk);
    for (int e = lo + threadIdx.x; e < hi; e += 256)
        atomicAdd(&lcnt[ed[e] >> BSHIFT], 1);
    __syncthreads();
    for (int b = threadIdx.x; b < NB; b += 256)
        if (lcnt[b]) atomicAdd(&bsize[b], lcnt[b]);
}
__global__ void k_bucket_scan(const int* __restrict__ bsize, int* __restrict__ bbase,
                              int* __restrict__ gcur, int NB) {
    int lane = threadIdx.x;
    if (lane >= 64) return;
    int carry = 0;
    int rounds = (NB + 63) / 64;
    for (int r = 0; r < rounds; ++r) {
        int idx = r * 64 + lane;
        int orig = (idx < NB) ? bsize[idx] : 0;
        int v = orig;
#pragma unroll
        for (int o = 1; o < 64; o <<= 1) {
            int t = __shfl_up(v, o, 64);
            if (lane >= o) v += t;
        }
        if (idx < NB) {
            int excl = carry + v - orig;
            bbase[idx] = excl;
            gcur[idx] = excl;
        }
        carry += __shfl(v, 63, 64);
    }
}
// packed: (src << 9) | (dst & 511)
__global__ void k_bin_write(const int* __restrict__ es, const int* __restrict__ ed,
                            int* __restrict__ gcur, unsigned* __restrict__ binned,
                            int E, int NB) {
    __shared__ int lcnt[1024];
    __shared__ int lofs[1024];
    int chunk = (E + gridDim.x - 1) / gridDim.x;
    int lo = blockIdx.x * chunk;
    int hi = min(E, lo + chunk);
    for (int i = threadIdx.x; i < NB; i += 256) lcnt[i] = 0;
    __syncthreads();
    for (int e = lo + threadIdx.x; e < hi; e += 256)
        atomicAdd(&lcnt[ed[e] >> BSHIFT], 1);
    __syncthreads();
    for (int b = threadIdx.x; b < NB; b += 256) {
        int c = lcnt[b];
        lofs[b] = c ? atomicAdd(&gcur[b], c) : 0;
    }
    __syncthreads();
    for (int i = threadIdx.x; i < NB; i += 256) lcnt[i] = 0;
    __syncthreads();
    for (int e = lo + threadIdx.x; e < hi; e += 256) {
        int s = es[e], t = ed[e];
        int b = t >> BSHIFT;
        int pos = lofs[b] + atomicAdd(&lcnt[b], 1);
        binned[pos] = ((unsigned)s << BSHIFT) | (unsigned)(t & (NPBK - 1));
    }
}
__global__ void k_csr_build(const unsigned* __restrict__ binned, const int* __restrict__ bbase,
                            const int* __restrict__ bsize, int* __restrict__ rowptr,
                            int* __restrict__ deg, float* __restrict__ dinv,
                            int* __restrict__ csrc, int N) {
    __shared__ int cnt_l[NPBK];
    __shared__ int ofs_l[NPBK];
    int b = blockIdx.x;
    int base = bbase[b];
    int cnt = bsize[b];
    int nlo = b << BSHIFT;
    int nhi = min(N, nlo + NPBK);
    int nv = nhi - nlo;
    int csrbase = base + nlo;
    int tid = threadIdx.x;
    for (int i = tid; i < NPBK; i += 256) cnt_l[i] = (i < nv) ? 1 : 0;
    __syncthreads();
    for (int e = tid; e < cnt; e += 256)
        atomicAdd(&cnt_l[binned[base + e] & (NPBK - 1)], 1);
    __syncthreads();
    if (tid < 64) {
        int carry = 0;
#pragma unroll
        for (int r = 0; r < NPBK / 64; ++r) {
            int idx = r * 64 + tid;
            int orig = cnt_l[idx];
            int v = orig;
#pragma unroll
            for (int o = 1; o < 64; o <<= 1) {
                int t = __shfl_up(v, o, 64);
                if (tid >= o) v += t;
            }
            ofs_l[idx] = carry + v - orig;
            carry += __shfl(v, 63, 64);
        }
    }
    __syncthreads();
    for (int i = tid; i < nv; i += 256) {
        int node = nlo + i;
        int d = cnt_l[i];
        rowptr[node] = csrbase + ofs_l[i];
        deg[node] = d;
        dinv[node] = rsqrtf((float)d);
    }
    __syncthreads();
    for (int i = tid; i < NPBK; i += 256) cnt_l[i] = ofs_l[i];
    __syncthreads();
    for (int e = tid; e < cnt; e += 256) {
        unsigned u = binned[base + e];
        int p = atomicAdd(&cnt_l[u & (NPBK - 1)], 1);
        csrc[csrbase + p] = (int)(u >> BSHIFT);
    }
    for (int i = tid; i < nv; i += 256) {
        int p = atomicAdd(&cnt_l[i], 1);
        csrc[csrbase + p] = nlo + i;
    }
}

// ===================== xh = half(x * dinv[row]) =====================
__global__ void k_cvt_xh(const float* __restrict__ x, const float* __restrict__ dinv,
                         half_t* __restrict__ xh, int n) {
    int total = n * 8;
    for (int q = blockIdx.x * blockDim.x + threadIdx.x; q < total;
         q += gridDim.x * blockDim.x) {
        float din = dinv[q >> 3];
        float4 a = ((const float4*)x)[q * 2];
        float4 b = ((const float4*)x)[q * 2 + 1];
        halfv8 h;
        h[0] = (half_t)(a.x * din); h[1] = (half_t)(a.y * din);
        h[2] = (half_t)(a.z * din); h[3] = (half_t)(a.w * din);
        h[4] = (half_t)(b.x * din); h[5] = (half_t)(b.y * din);
        h[6] = (half_t)(b.z * din); h[7] = (half_t)(b.w * din);
        ((halfv8*)xh)[q] = h;
    }
}

// ===== dense matmul; half in, half out; 8-row register blocking =====
// EPI 1: +bias, BN, ReLU;  EPI 2: * dinv[row]
template <int K, int M, int EPI>
__global__ void k_matmulh(const half_t* __restrict__ X, const float* __restrict__ W,
                          half_t* __restrict__ Y, int n,
                          const float* __restrict__ b, const float* __restrict__ g,
                          const float* __restrict__ be, const float* __restrict__ m,
                          const float* __restrict__ v, const float* __restrict__ dinv) {
    __shared__ float Wl[K * M];
    for (int i = threadIdx.x; i < K * M / 4; i += 256)
        ((float4*)Wl)[i] = ((const float4*)W)[i];
    __syncthreads();
    const int TPR = M / 4;            // threads across columns
    const int GPB = 256 / TPR;        // 8-row groups per block
    int grp = blockIdx.x * GPB + threadIdx.x / TPR;
    int row0 = grp * 8;
    if (row0 >= n) return;
    int nr = n - row0; if (nr > 8) nr = 8;
    const int c4 = (threadIdx.x % TPR) * 4;
    const half_t* xp[8];
#pragma unroll
    for (int r = 0; r < 8; ++r) {
        int rr = (r < nr) ? r : (nr - 1);
        xp[r] = X + (long long)(row0 + rr) * K;
    }
    float4 acc[8];
#pragma unroll
    for (int r = 0; r < 8; ++r) acc[r] = make_float4(0.f, 0.f, 0.f, 0.f);
#pragma unroll
    for (int k8 = 0; k8 < K / 8; ++k8) {
        halfv8 xv[8];
#pragma unroll
        for (int r = 0; r < 8; ++r)
            xv[r] = *(const halfv8*)(xp[r] + k8 * 8);
#pragma unroll
        for (int j = 0; j < 8; ++j) {
            float4 wv = *(const float4*)&Wl[(k8 * 8 + j) * M + c4];
#pragma unroll
            for (int r = 0; r < 8; ++r) {
                float xs = (float)xv[r][j];
                acc[r].x += xs * wv.x; acc[r].y += xs * wv.y;
                acc[r].z += xs * wv.z; acc[r].w += xs * wv.w;
            }
        }
    }
    float4 bb, mm, vv, gg, ee;
    if (EPI == 1) {
        bb = *(const float4*)(b + c4);
        mm = *(const float4*)(m + c4);
        vv = *(const float4*)(v + c4);
        gg = *(const float4*)(g + c4);
        ee = *(const float4*)(be + c4);
    }
#pragma unroll
    for (int r = 0; r < 8; ++r) {
        if (r >= nr) break;
        float4 a = acc[r];
        if (EPI == 1) {
            a.x = fmaxf((a.x + bb.x - mm.x) * rsqrtf(vv.x + EPSN) * gg.x + ee.x, 0.f);
            a.y = fmaxf((a.y + bb.y - mm.y) * rsqrtf(vv.y + EPSN) * gg.y + ee.y, 0.f);
            a.z = fmaxf((a.z + bb.z - mm.z) * rsqrtf(vv.z + EPSN) * gg.z + ee.z, 0.f);
            a.w = fmaxf((a.w + bb.w - mm.w) * rsqrtf(vv.w + EPSN) * gg.w + ee.w, 0.f);
        } else {
            float din = dinv[row0 + r];
            a.x *= din; a.y *= din; a.z *= din; a.w *= din;
        }
        halfv4 hv;
        hv[0] = (half_t)a.x; hv[1] = (half_t)a.y;
        hv[2] = (half_t)a.z; hv[3] = (half_t)a.w;
        *(halfv4*)(Y + (long long)(row0 + r) * M + c4) = hv;
    }
}

// ===== CSR sum-aggregation over half rows, 8 dims/lane, unroll-2; half out =====
template <int M, int EPI>
__global__ void k_agg4h(const half_t* __restrict__ A, const int* __restrict__ rowptr,
                        const int* __restrict__ deg, const int* __restrict__ csrc,
                        const float* __restrict__ dinv,
                        const float* __restrict__ b, const float* __restrict__ g,
                        const float* __restrict__ be, const float* __restrict__ m,
                        const float* __restrict__ v,
                        half_t* __restrict__ B, int n) {
    const int LPE = M / 8;
    const int EPW = 64 / LPE;
    int node = blockIdx.x * 4 + (threadIdx.x >> 6);
    if (node >= n) return;
    int lane = threadIdx.x & 63;
    int eg = lane / LPE;
    int dl = lane % LPE;
    int beg = rowptr[node];
    int end = beg + deg[node];
    float acc[8];
#pragma unroll
    for (int j = 0; j < 8; ++j) acc[j] = 0.f;
    int i = beg + eg;
    for (; i + EPW < end; i += 2 * EPW) {
        int s0 = csrc[i];
        int s1 = csrc[i + EPW];
        halfv8 x0 = *(const halfv8*)(A + (long long)s0 * M + dl * 8);
        halfv8 x1 = *(const halfv8*)(A + (long long)s1 * M + dl * 8);
#pragma unroll
        for (int j = 0; j < 8; ++j) acc[j] += (float)x0[j] + (float)x1[j];
    }
    if (i < end) {
        int s = csrc[i];
        halfv8 xv = *(const halfv8*)(A + (long long)s * M + dl * 8);
#pragma unroll
        for (int j = 0; j < 8; ++j) acc[j] += (float)xv[j];
    }
#pragma unroll
    for (int off = LPE; off < 64; off <<= 1) {
#pragma unroll
        for (int j = 0; j < 8; ++j) acc[j] += __shfl_xor(acc[j], off);
    }
    if (eg == 0) {
        float din = dinv[node];
        int d0 = dl * 8;
        float o[8];
#pragma unroll
        for (int j = 0; j < 8; ++j) o[j] = acc[j] * din;
        if (EPI == 1) {
#pragma unroll
            for (int j = 0; j < 8; ++j) {
                int d = d0 + j;
                o[j] = fmaxf((o[j] + b[d] - m[d]) * rsqrtf(v[d] + EPSN) * g[d] + be[d], 0.f);
            }
        }
        halfv8 hw;
#pragma unroll
        for (int j = 0; j < 8; ++j) hw[j] = (half_t)o[j];
        *(halfv8*)(B + (long long)node * M + d0) = hw;
    }
}

// ===== tiny: Ws/Wd = Wg folded with ags/agd -> wsd[2][32][4] =====
__global__ void k_wsd(const float* __restrict__ Wg, const float* __restrict__ ags,
                      const float* __restrict__ agd, float* __restrict__ wsd) {
    int j = threadIdx.x;
    if (j < 128) {
        int k = j >> 2, h = j & 3;
        float ss = 0.f, dd = 0.f;
        for (int d2 = 0; d2 < 32; ++d2) {
            float wv = Wg[k * 128 + h * 32 + d2];
            ss += wv * ags[h * 32 + d2];
            dd += wv * agd[h * 32 + d2];
        }
        wsd[j] = ss;
        wsd[128 + j] = dd;
    }
}

// ===== layer-3 agg (M=32, half in) + BN/ReLU + fused attention coefs; H3 half out =====
__global__ void k_agg_att(const half_t* __restrict__ A, const int* __restrict__ rowptr,
                          const int* __restrict__ deg, const int* __restrict__ csrc,
                          const float* __restrict__ dinv,
                          const float* __restrict__ b, const float* __restrict__ g,
                          const float* __restrict__ be, const float* __restrict__ m,
                          const float* __restrict__ v, const float* __restrict__ wsd,
                          half_t* __restrict__ H3h, float* __restrict__ a_s,
                          float* __restrict__ a_d, int n) {
    __shared__ float Wl[256];
    for (int i = threadIdx.x; i < 256; i += 256) Wl[i] = wsd[i];
    __syncthreads();
    const int M = 32, EPW = 16;
    int node = blockIdx.x * 4 + (threadIdx.x >> 6);
    if (node >= n) return;
    int lane = threadIdx.x & 63;
    int eg = lane >> 2;      // 16 edge slots
    int dl = lane & 3;       // 4 lanes/row, 8 dims each
    int beg = rowptr[node];
    int end = beg + deg[node];
    float acc[8];
#pragma unroll
    for (int j = 0; j < 8; ++j) acc[j] = 0.f;
    int i = beg + eg;
    for (; i + EPW < end; i += 2 * EPW) {
        int s0 = csrc[i];
        int s1 = csrc[i + EPW];
        halfv8 x0 = *(const halfv8*)(A + (long long)s0 * M + dl * 8);
        halfv8 x1 = *(const halfv8*)(A + (long long)s1 * M + dl * 8);
#pragma unroll
        for (int j = 0; j < 8; ++j) acc[j] += (float)x0[j] + (float)x1[j];
    }
    if (i < end) {
        int s = csrc[i];
        halfv8 xv = *(const halfv8*)(A + (long long)s * M + dl * 8);
#pragma unroll
        for (int j = 0; j < 8; ++j) acc[j] += (float)xv[j];
    }
#pragma unroll
    for (int off = 4; off < 64; off <<= 1) {
#pragma unroll
        for (int j = 0; j < 8; ++j) acc[j] += __shfl_xor(acc[j], off);
    }
    float din = dinv[node];
    int d0 = dl * 8;
    float hv[8];
#pragma unroll
    for (int j = 0; j < 8; ++j) {
        int d = d0 + j;
        hv[j] = fmaxf((acc[j] * din + b[d] - m[d]) * rsqrtf(v[d] + EPSN) * g[d] + be[d], 0.f);
    }
    if (eg == 0) {
        halfv8 hw;
#pragma unroll
        for (int j = 0; j < 8; ++j) hw[j] = (half_t)hv[j];
        *(halfv8*)(H3h + (long long)node * M + d0) = hw;
    }
    // attention coefs via shfl from lanes 0..3 (dl=0..3, eg=0)
    int h = lane & 3, sel = (lane >> 2) & 1;
    const float* wp = &Wl[sel * 128];
    float o = 0.f;
#pragma unroll
    for (int src = 0; src < 4; ++src) {
#pragma unroll
        for (int j = 0; j < 8; ++j) {
            float xv = __shfl(hv[j], src);
            o += xv * wp[(src * 8 + j) * 4 + h];
        }
    }
    if (lane < 4) a_s[node * 4 + h] = o;
    else if (lane < 8) a_d[node * 4 + h] = o;
}

// ===== fused GAT: softmax + half2 gather + Wg epilogue + partial pooling =====
__global__ void k_gat4(const half_t* __restrict__ H3h, const float* __restrict__ a_s,
                       const float* __restrict__ a_d, const int* __restrict__ rowptr,
                       const int* __restrict__ deg, const int* __restrict__ csrc,
                       const float* __restrict__ Wg, const float* __restrict__ bg,
                       const int* __restrict__ batch, float* __restrict__ pooled_part,
                       int n) {
    __shared__ float sc[4][GCAP * 4];   // [w][e*4+h]
    __shared__ int   srcb[4][GCAP];
    __shared__ float wb[4][128];
    int w = threadIdx.x >> 6;
    int node = blockIdx.x * 4 + w;
    if (node >= n) return;
    int lane = threadIdx.x & 63;
    int beg = rowptr[node];
    int cnt = deg[node];
    bool fits = (cnt <= GCAP);
    float4 ad4 = ((const float4*)a_d)[node];
    float m0 = -1e30f, m1 = -1e30f, m2 = -1e30f, m3 = -1e30f;
    if (fits) {
        for (int e = lane; e < cnt; e += 64) {
            int s = csrc[beg + e];
            srcb[w][e] = s;
            float4 as = ((const float4*)a_s)[s];
            float e0 = lrelu(as.x + ad4.x);
            float e1 = lrelu(as.y + ad4.y);
            float e2 = lrelu(as.z + ad4.z);
            float e3 = lrelu(as.w + ad4.w);
            *(float4*)&sc[w][e * 4] = make_float4(e0, e1, e2, e3);
            m0 = fmaxf(m0, e0); m1 = fmaxf(m1, e1);
            m2 = fmaxf(m2, e2); m3 = fmaxf(m3, e3);
        }
    } else {
        for (int e = lane; e < cnt; e += 64) {
            int s = csrc[beg + e];
            float4 as = ((const float4*)a_s)[s];
            m0 = fmaxf(m0, lrelu(as.x + ad4.x));
            m1 = fmaxf(m1, lrelu(as.y + ad4.y));
            m2 = fmaxf(m2, lrelu(as.z + ad4.z));
            m3 = fmaxf(m3, lrelu(as.w + ad4.w));
        }
    }
#pragma unroll
    for (int o = 1; o < 64; o <<= 1) {
        m0 = fmaxf(m0, __shfl_xor(m0, o));
        m1 = fmaxf(m1, __shfl_xor(m1, o));
        m2 = fmaxf(m2, __shfl_xor(m2, o));
        m3 = fmaxf(m3, __shfl_xor(m3, o));
    }
    float s0 = 0.f, s1 = 0.f, s2 = 0.f, s3 = 0.f;
    if (fits) {
        for (int e = lane; e < cnt; e += 64) {
            float4 sv = *(float4*)&sc[w][e * 4];
            float p0 = __expf(sv.x - m0);
            float p1 = __expf(sv.y - m1);
            float p2 = __expf(sv.z - m2);
            float p3 = __expf(sv.w - m3);
            *(float4*)&sc[w][e * 4] = make_float4(p0, p1, p2, p3);
            s0 += p0; s1 += p1; s2 += p2; s3 += p3;
        }
    } else {
        for (int e = lane; e < cnt; e += 64) {
            int s = csrc[beg + e];
            float4 as = ((const float4*)a_s)[s];
            s0 += __expf(lrelu(as.x + ad4.x) - m0);
            s1 += __expf(lrelu(as.y + ad4.y) - m1);
            s2 += __expf(lrelu(as.z + ad4.z) - m2);
            s3 += __expf(lrelu(as.w + ad4.w) - m3);
        }
    }
#pragma unroll
    for (int o = 1; o < 64; o <<= 1) {
        s0 += __shfl_xor(s0, o);
        s1 += __shfl_xor(s1, o);
        s2 += __shfl_xor(s2, o);
        s3 += __shfl_xor(s3, o);
    }
    float inv0 = 0.25f / s0, inv1 = 0.25f / s1, inv2 = 0.25f / s2, inv3 = 0.25f / s3;
    // phase 2: quarter-wave per edge; lane -> q=lane>>4, k=lane&15 (dims 2k,2k+1)
    int q = lane >> 4;
    int k = lane & 15;
    float acc[8];
#pragma unroll
    for (int j = 0; j < 8; ++j) acc[j] = 0.f;
    if (fits) {
        int i = q;
        for (; i + 4 < cnt; i += 8) {
            int sA = srcb[w][i];
            int sB = srcb[w][i + 4];
            halfv2 xA = *(const halfv2*)(H3h + (long long)sA * 32 + 2 * k);
            halfv2 xB = *(const halfv2*)(H3h + (long long)sB * 32 + 2 * k);
            float4 wA = *(float4*)&sc[w][i * 4];
            float4 wB = *(float4*)&sc[w][(i + 4) * 4];
            float a0 = (float)xA[0], a1 = (float)xA[1];
            float b0 = (float)xB[0], b1 = (float)xB[1];
            acc[0] += wA.x * a0 + wB.x * b0; acc[1] += wA.x * a1 + wB.x * b1;
            acc[2] += wA.y * a0 + wB.y * b0; acc[3] += wA.y * a1 + wB.y * b1;
            acc[4] += wA.z * a0 + wB.z * b0; acc[5] += wA.z * a1 + wB.z * b1;
            acc[6] += wA.w * a0 + wB.w * b0; acc[7] += wA.w * a1 + wB.w * b1;
        }
        if (i < cnt) {
            int s = srcb[w][i];
            halfv2 xv = *(const halfv2*)(H3h + (long long)s * 32 + 2 * k);
            float4 wv = *(float4*)&sc[w][i * 4];
            float x0 = (float)xv[0], x1 = (float)xv[1];
            acc[0] += wv.x * x0; acc[1] += wv.x * x1;
            acc[2] += wv.y * x0; acc[3] += wv.y * x1;
            acc[4] += wv.z * x0; acc[5] += wv.z * x1;
            acc[6] += wv.w * x0; acc[7] += wv.w * x1;
        }
    } else {
        for (int i = q; i < cnt; i += 4) {
            int s = csrc[beg + i];
            float4 as = ((const float4*)a_s)[s];
            float p0 = __expf(lrelu(as.x + ad4.x) - m0);
            float p1 = __expf(lrelu(as.y + ad4.y) - m1);
            float p2 = __expf(lrelu(as.z + ad4.z) - m2);
            float p3 = __expf(lrelu(as.w + ad4.w) - m3);
            halfv2 xv = *(const halfv2*)(H3h + (long long)s * 32 + 2 * k);
            float x0 = (float)xv[0], x1 = (float)xv[1];
            acc[0] += p0 * x0; acc[1] += p0 * x1;
            acc[2] += p1 * x0; acc[3] += p1 * x1;
            acc[4] += p2 * x0; acc[5] += p2 * x1;
            acc[6] += p3 * x0; acc[7] += p3 * x1;
        }
    }
#pragma unroll
    for (int o = 16; o < 64; o <<= 1) {
#pragma unroll
        for (int j = 0; j < 8; ++j) acc[j] += __shfl_xor(acc[j], o);
    }
    if (q == 0) {
        float invh[4] = {inv0, inv1, inv2, inv3};
#pragma unroll
        for (int h = 0; h < 4; ++h) {
            wb[w][h * 32 + 2 * k]     = acc[h * 2]     * invh[h];
            wb[w][h * 32 + 2 * k + 1] = acc[h * 2 + 1] * invh[h];
        }
    }
    // epilogue + partial pooling (no H4 materialization)
    int d = lane & 31;
    int h0 = lane >> 5;
    int half_ = h0 * 64;
    float o = 0.f;
#pragma unroll
    for (int j = 0; j < 64; ++j) {
        int jj = half_ + j;
        o += wb[w][jj] * Wg[(jj & 31) * 128 + (jj >> 5) * 32 + d];
    }
    o += __shfl_xor(o, 32);
    if (lane < 32) {
        float val = fmaxf(o + bg[d], 0.f);
        int g = batch[node];
        float* pp = pooled_part + (size_t)(blockIdx.x & (NPART - 1)) * PSTR;
        atomicAdd(&pp[g * 32 + d], val);
        if (d == 0) atomicAdd(&pp[NGRAPH * 32 + g], 1.f);
    }
}

// ===================== pool reduce (partials -> pooled+cnt) =====================
__global__ void k_pool_reduce(const float* __restrict__ part, float* __restrict__ outp) {
    int i = blockIdx.x * blockDim.x + threadIdx.x;
    if (i >= PSTR) return;
    float s = 0.f;
#pragma unroll 8
    for (int c = 0; c < NPART; ++c) s += part[(size_t)c * PSTR + i];
    outp[i] = s;
}

// ===================== classifier =====================
__global__ void k_classifier(const float* __restrict__ pooled, const float* __restrict__ cnt,
                             const float* __restrict__ Wc1, const float* __restrict__ bc1,
                             const float* __restrict__ Wc2, const float* __restrict__ bc2,
                             float* __restrict__ out) {
    __shared__ float pl[NGRAPH * 32];
    __shared__ float t1[NGRAPH * 16];
    int tid = threadIdx.x;
    for (int i = tid; i < NGRAPH * 32; i += blockDim.x) {
        int g = i >> 5;
        pl[i] = pooled[i] / fmaxf(cnt[g], 1.f);
    }
    __syncthreads();
    for (int i = tid; i < NGRAPH * 16; i += blockDim.x) {
        int g = i >> 4, c = i & 15;
        float acc = bc1[c];
#pragma unroll
        for (int d = 0; d < 32; ++d) acc += pl[g * 32 + d] * Wc1[d * 16 + c];
        t1[i] = fmaxf(acc, 0.f);
    }
    __syncthreads();
    for (int i = tid; i < NGRAPH * 5; i += blockDim.x) {
        int g = i / 5, c = i % 5;
        float acc = bc2[c];
#pragma unroll
        for (int k = 0; k < 16; ++k) acc += t1[g * 16 + k] * Wc2[k * 5 + c];
        out[i] = acc;
    }
}

// ===================== launch =====================
static inline dim3 gsz(long long work, int block = 256) {
    long long g = (work + block - 1) / block;
    if (g > 262144) g = 262144;
    if (g < 1) g = 1;
    return dim3((unsigned)g);
}

extern "C" void kernel_launch(void* const* d_in, const int* in_sizes, int n_in,
                              void* d_out, int out_size, void* d_ws, size_t ws_size,
                              hipStream_t stream) {
    const float* x     = (const float*)d_in[0];
    const int*   ei    = (const int*)d_in[1];
    const int*   batch = (const int*)d_in[2];
    const float* W1 = (const float*)d_in[3];  const float* b1 = (const float*)d_in[4];
    const float* W2 = (const float*)d_in[5];  const float* b2 = (const float*)d_in[6];
    const float* W3 = (const float*)d_in[7];  const float* b3 = (const float*)d_in[8];
    const float* g1 = (const float*)d_in[9];  const float* be1 = (const float*)d_in[10];
    const float* m1 = (const float*)d_in[11]; const float* v1  = (const float*)d_in[12];
    const float* g2 = (const float*)d_in[13]; const float* be2 = (const float*)d_in[14];
    const float* m2 = (const float*)d_in[15]; const float* v2  = (const float*)d_in[16];
    const float* g3 = (const float*)d_in[17]; const float* be3 = (const float*)d_in[18];
    const float* m3 = (const float*)d_in[19]; const float* v3  = (const float*)d_in[20];
    const float* Wg  = (const float*)d_in[21];
    const float* ags = (const float*)d_in[22];
    const float* agd = (const float*)d_in[23];
    const float* bg  = (const float*)d_in[24];
    const float* Wc1 = (const float*)d_in[25]; const float* bc1 = (const float*)d_in[26];
    const float* Wc2 = (const float*)d_in[27]; const float* bc2 = (const float*)d_in[28];
    float* out = (float*)d_out;

    const int N = in_sizes[0] / 64;
    const int E = in_sizes[1] / 2;
    const int* esrc = ei;
    const int* edst = ei + E;
    const int NB = (N + NPBK - 1) >> BSHIFT;

    size_t off = 0;
    auto take = [&](size_t bytes) -> void* {
        void* p = (char*)d_ws + off;
        off += bytes;
        off = (off + 255) & ~(size_t)255;
        return p;
    };
    int*    deg    = (int*)take((size_t)N * 4);
    float*  dinv   = (float*)take((size_t)N * 4);
    int*    rowptr = (int*)take((size_t)N * 4);
    int*    bsize  = (int*)take((size_t)1024 * 4);
    int*    bbase  = (int*)take((size_t)1024 * 4);
    int*    gcur   = (int*)take((size_t)1024 * 4);
    float*  wsd    = (float*)take((size_t)256 * 4);
    int*    csrc   = (int*)take((size_t)(E + N) * 4);
    half_t* bufAh  = (half_t*)take((size_t)N * 64 * 2);  // xh -> A2h -> A3h
    half_t* bufBh  = (half_t*)take((size_t)N * 64 * 2);  // Xa -> H2
    float*  bufC   = (float*)take((size_t)N * 128 * 4);  // binned(u32,E) ; H1h (half,N*128)
    half_t* h3h    = (half_t*)take((size_t)N * 32 * 2);
    float*  a_s    = (float*)take((size_t)N * 4 * 4);
    float*  a_d    = (float*)take((size_t)N * 4 * 4);
    float*  ppart  = (float*)take((size_t)NPART * PSTR * 4);
    float*  pooled = (float*)take((size_t)PSTR * 4);
    float*  cnt    = pooled + NGRAPH * 32;
    unsigned* binned = (unsigned*)bufC;
    half_t* H1h    = (half_t*)bufC;                      // binned dead before H1 written
    (void)ws_size; (void)n_in; (void)out_size;

    const dim3 B256(256);

    // ---- binned CSR build ----
    hipMemsetAsync(bsize, 0, (size_t)NB * 4, stream);
    hipMemsetAsync(ppart, 0, (size_t)NPART * PSTR * 4, stream);
    hipLaunchKernelGGL(k_bin_count, dim3(512), B256, 0, stream, edst, bsize, E, NB);
    hipLaunchKernelGGL(k_bucket_scan, dim3(1), dim3(64), 0, stream, bsize, bbase, gcur, NB);
    hipLaunchKernelGGL(k_bin_write, dim3(512), B256, 0, stream, esrc, edst, gcur, binned, E, NB);
    hipLaunchKernelGGL(k_csr_build, dim3(NB), B256, 0, stream,
                       binned, bbase, bsize, rowptr, deg, dinv, csrc, N);
    hipLaunchKernelGGL(k_wsd, dim3(1), dim3(128), 0, stream, Wg, ags, agd, wsd);

    // ---- layer 1: xh = half(x*dinv); Xa = half(dinv*sum(xh)); H1h = half(relu(BN(Xa@W1+b1)))
    hipLaunchKernelGGL(k_cvt_xh, gsz((long long)N * 8), B256, 0, stream, x, dinv, bufAh, N);
    hipLaunchKernelGGL((k_agg4h<64, 0>), dim3((N + 3) / 4), B256, 0, stream,
                       bufAh, rowptr, deg, csrc, dinv,
                       nullptr, nullptr, nullptr, nullptr, nullptr, bufBh, N);
    hipLaunchKernelGGL((k_matmulh<64, 128, 1>), dim3((N + 63) / 64), B256, 0, stream,
                       bufBh, W1, H1h, N, b1, g1, be1, m1, v1, nullptr);
    // ---- layer 2: A2h = half((H1@W2)*dinv); H2 = half(relu(BN(dinv*sum(A2h)+b2)))
    hipLaunchKernelGGL((k_matmulh<128, 64, 2>), dim3((N + 127) / 128), B256, 0, stream,
                       H1h, W2, bufAh, N, nullptr, nullptr, nullptr, nullptr, nullptr, dinv);
    hipLaunchKernelGGL((k_agg4h<64, 1>), dim3((N + 3) / 4), B256, 0, stream,
                       bufAh, rowptr, deg, csrc, dinv, b2, g2, be2, m2, v2, bufBh, N);
    // ---- layer 3: A3h = half((H2@W3)*dinv); H3h + a_s/a_d fused
    hipLaunchKernelGGL((k_matmulh<64, 32, 2>), dim3((N + 255) / 256), B256, 0, stream,
                       bufBh, W3, bufAh, N, nullptr, nullptr, nullptr, nullptr, nullptr, dinv);
    hipLaunchKernelGGL(k_agg_att, dim3((N + 3) / 4), B256, 0, stream,
                       bufAh, rowptr, deg, csrc, dinv, b3, g3, be3, m3, v3,
                       wsd, h3h, a_s, a_d, N);

    // ---- GAT (half H3 gather; pooling fused via partials, no H4)
    hipLaunchKernelGGL(k_gat4, dim3((N + 3) / 4), B256, 0, stream,
                       h3h, a_s, a_d, rowptr, deg, csrc, Wg, bg, batch, ppart, N);

    // ---- pool reduce + classifier
    hipLaunchKernelGGL(k_pool_reduce, dim3((PSTR + 255) / 256), B256, 0, stream, ppart, pooled);
    hipLaunchKernelGGL(k_classifier, dim3(1), B256, 0, stream, pooled, cnt, Wc1, bc1, Wc2, bc2, out);
}

// Round 13
// 557.457 us; speedup vs baseline: 3.3001x; 3.3001x over previous
//
#include <hip/hip_runtime.h>

#define EPSN   1e-5f
#define NEGS   0.2f
#define NGRAPH 64
#define BSHIFT 9
#define NPBK   512            // nodes per bucket = 1<<BSHIFT
#define GCAP   96             // GAT LDS edge cap per node
#define NPART  64             // pooled partial copies (contention spreading)
#define PSTR   (NGRAPH * 32 + NGRAPH)   // 2112 floats per partial copy

typedef _Float16 half_t;
typedef _Float16 halfv8 __attribute__((ext_vector_type(8)));
typedef _Float16 halfv4 __attribute__((ext_vector_type(4)));
typedef _Float16 halfv2 __attribute__((ext_vector_type(2)));

__device__ __forceinline__ float lrelu(float e) { return e > 0.f ? e : NEGS * e; }

// ===================== binned CSR build =====================
__global__ void k_bin_count(const int* __restrict__ ed, int* __restrict__ bsize,
                            int E, int NB) {
    __shared__ int lcnt[1024];
    for (int i = threadIdx.x; i < NB; i += 256) lcnt[i] = 0;
    __syncthreads();
    int chunk = (E + gridDim.x - 1) / gridDim.x;
    int lo = blockIdx.x * chunk;
    int hi = min(E, lo + chunk);
    for (int e = lo + threadIdx.x; e < hi; e += 256)
        atomicAdd(&lcnt[ed[e] >> BSHIFT], 1);
    __syncthreads();
    for (int b = threadIdx.x; b < NB; b += 256)
        if (lcnt[b]) atomicAdd(&bsize[b], lcnt[b]);
}
__global__ void k_bucket_scan(const int* __restrict__ bsize, int* __restrict__ bbase,
                              int* __restrict__ gcur, int NB) {
    int lane = threadIdx.x;
    if (lane >= 64) return;
    int carry = 0;
    int rounds = (NB + 63) / 64;
    for (int r = 0; r < rounds; ++r) {
        int idx = r * 64 + lane;
        int orig = (idx < NB) ? bsize[idx] : 0;
        int v = orig;
#pragma unroll
        for (int o = 1; o < 64; o <<= 1) {
            int t = __shfl_up(v, o, 64);
            if (lane >= o) v += t;
        }
        if (idx < NB) {
            int excl = carry + v - orig;
            bbase[idx] = excl;
            gcur[idx] = excl;
        }
        carry += __shfl(v, 63, 64);
    }
}
// packed: (src << 9) | (dst & 511)
__global__ void k_bin_write(const int* __restrict__ es, const int* __restrict__ ed,
                            int* __restrict__ gcur, unsigned* __restrict__ binned,
                            int E, int NB) {
    __shared__ int lcnt[1024];
    __shared__ int lofs[1024];
    int chunk = (E + gridDim.x - 1) / gridDim.x;
    int lo = blockIdx.x * chunk;
    int hi = min(E, lo + chunk);
    for (int i = threadIdx.x; i < NB; i += 256) lcnt[i] = 0;
    __syncthreads();
    for (int e = lo + threadIdx.x; e < hi; e += 256)
        atomicAdd(&lcnt[ed[e] >> BSHIFT], 1);
    __syncthreads();
    for (int b = threadIdx.x; b < NB; b += 256) {
        int c = lcnt[b];
        lofs[b] = c ? atomicAdd(&gcur[b], c) : 0;
    }
    __syncthreads();
    for (int i = threadIdx.x; i < NB; i += 256) lcnt[i] = 0;
    __syncthreads();
    for (int e = lo + threadIdx.x; e < hi; e += 256) {
        int s = es[e], t = ed[e];
        int b = t >> BSHIFT;
        int pos = lofs[b] + atomicAdd(&lcnt[b], 1);
        binned[pos] = ((unsigned)s << BSHIFT) | (unsigned)(t & (NPBK - 1));
    }
}
__global__ void k_csr_build(const unsigned* __restrict__ binned, const int* __restrict__ bbase,
                            const int* __restrict__ bsize, int* __restrict__ rowptr,
                            int* __restrict__ deg, float* __restrict__ dinv,
                            int* __restrict__ csrc, int N) {
    __shared__ int cnt_l[NPBK];
    __shared__ int ofs_l[NPBK];
    int b = blockIdx.x;
    int base = bbase[b];
    int cnt = bsize[b];
    int nlo = b << BSHIFT;
    int nhi = min(N, nlo + NPBK);
    int nv = nhi - nlo;
    int csrbase = base + nlo;
    int tid = threadIdx.x;
    for (int i = tid; i < NPBK; i += 256) cnt_l[i] = (i < nv) ? 1 : 0;
    __syncthreads();
    for (int e = tid; e < cnt; e += 256)
        atomicAdd(&cnt_l[binned[base + e] & (NPBK - 1)], 1);
    __syncthreads();
    if (tid < 64) {
        int carry = 0;
#pragma unroll
        for (int r = 0; r < NPBK / 64; ++r) {
            int idx = r * 64 + tid;
            int orig = cnt_l[idx];
            int v = orig;
#pragma unroll
            for (int o = 1; o < 64; o <<= 1) {
                int t = __shfl_up(v, o, 64);
                if (tid >= o) v += t;
            }
            ofs_l[idx] = carry + v - orig;
            carry += __shfl(v, 63, 64);
        }
    }
    __syncthreads();
    for (int i = tid; i < nv; i += 256) {
        int node = nlo + i;
        int d = cnt_l[i];
        rowptr[node] = csrbase + ofs_l[i];
        deg[node] = d;
        dinv[node] = rsqrtf((float)d);
    }
    __syncthreads();
    for (int i = tid; i < NPBK; i += 256) cnt_l[i] = ofs_l[i];
    __syncthreads();
    for (int e = tid; e < cnt; e += 256) {
        unsigned u = binned[base + e];
        int p = atomicAdd(&cnt_l[u & (NPBK - 1)], 1);
        csrc[csrbase + p] = (int)(u >> BSHIFT);
    }
    for (int i = tid; i < nv; i += 256) {
        int p = atomicAdd(&cnt_l[i], 1);
        csrc[csrbase + p] = nlo + i;
    }
}

// ===================== xh = half(x * dinv[row]) =====================
__global__ void k_cvt_xh(const float* __restrict__ x, const float* __restrict__ dinv,
                         half_t* __restrict__ xh, int n) {
    int total = n * 8;
    for (int q = blockIdx.x * blockDim.x + threadIdx.x; q < total;
         q += gridDim.x * blockDim.x) {
        float din = dinv[q >> 3];
        float4 a = ((const float4*)x)[q * 2];
        float4 b = ((const float4*)x)[q * 2 + 1];
        halfv8 h;
        h[0] = (half_t)(a.x * din); h[1] = (half_t)(a.y * din);
        h[2] = (half_t)(a.z * din); h[3] = (half_t)(a.w * din);
        h[4] = (half_t)(b.x * din); h[5] = (half_t)(b.y * din);
        h[6] = (half_t)(b.z * din); h[7] = (half_t)(b.w * din);
        ((halfv8*)xh)[q] = h;
    }
}

// ===== dense matmul; half in, half out; 4-row register blocking =====
// (scalar locals only — no per-thread arrays; tail clamped, duplicate
//  writes produce identical values so overlap is benign)
// EPI 1: +bias, BN, ReLU;  EPI 2: * dinv[row]
template <int K, int M, int EPI>
__global__ void k_matmulh(const half_t* __restrict__ X, const float* __restrict__ W,
                          half_t* __restrict__ Y, int n,
                          const float* __restrict__ b, const float* __restrict__ g,
                          const float* __restrict__ be, const float* __restrict__ m,
                          const float* __restrict__ v, const float* __restrict__ dinv) {
    __shared__ float Wl[K * M];
    for (int i = threadIdx.x; i < K * M / 4; i += 256)
        ((float4*)Wl)[i] = ((const float4*)W)[i];
    __syncthreads();
    const int TPR = M / 4;            // threads across columns
    const int GPB = 256 / TPR;        // 4-row groups per block
    int grp = blockIdx.x * GPB + threadIdx.x / TPR;
    int row0 = grp * 4;
    if (row0 >= n) return;
    if (row0 + 4 > n) row0 = n - 4;   // clamp; duplicated rows write same data
    const int c4 = (threadIdx.x % TPR) * 4;
    const half_t* xb = X + (long long)row0 * K;
    float4 acc0 = make_float4(0.f, 0.f, 0.f, 0.f);
    float4 acc1 = acc0, acc2 = acc0, acc3 = acc0;
#pragma unroll
    for (int k8 = 0; k8 < K / 8; ++k8) {
        halfv8 x0 = *(const halfv8*)(xb + k8 * 8);
        halfv8 x1 = *(const halfv8*)(xb + K + k8 * 8);
        halfv8 x2 = *(const halfv8*)(xb + 2 * K + k8 * 8);
        halfv8 x3 = *(const halfv8*)(xb + 3 * K + k8 * 8);
#pragma unroll
        for (int j = 0; j < 8; ++j) {
            float4 wv = *(const float4*)&Wl[(k8 * 8 + j) * M + c4];
            float s0 = (float)x0[j], s1 = (float)x1[j];
            float s2 = (float)x2[j], s3 = (float)x3[j];
            acc0.x += s0 * wv.x; acc0.y += s0 * wv.y; acc0.z += s0 * wv.z; acc0.w += s0 * wv.w;
            acc1.x += s1 * wv.x; acc1.y += s1 * wv.y; acc1.z += s1 * wv.z; acc1.w += s1 * wv.w;
            acc2.x += s2 * wv.x; acc2.y += s2 * wv.y; acc2.z += s2 * wv.z; acc2.w += s2 * wv.w;
            acc3.x += s3 * wv.x; acc3.y += s3 * wv.y; acc3.z += s3 * wv.z; acc3.w += s3 * wv.w;
        }
    }
    float4 bb, mm, vv, gg, ee;
    if (EPI == 1) {
        bb = *(const float4*)(b + c4);
        mm = *(const float4*)(m + c4);
        vv = *(const float4*)(v + c4);
        gg = *(const float4*)(g + c4);
        ee = *(const float4*)(be + c4);
    }
#pragma unroll
    for (int r = 0; r < 4; ++r) {
        float4 a = (r == 0) ? acc0 : (r == 1) ? acc1 : (r == 2) ? acc2 : acc3;
        if (EPI == 1) {
            a.x = fmaxf((a.x + bb.x - mm.x) * rsqrtf(vv.x + EPSN) * gg.x + ee.x, 0.f);
            a.y = fmaxf((a.y + bb.y - mm.y) * rsqrtf(vv.y + EPSN) * gg.y + ee.y, 0.f);
            a.z = fmaxf((a.z + bb.z - mm.z) * rsqrtf(vv.z + EPSN) * gg.z + ee.z, 0.f);
            a.w = fmaxf((a.w + bb.w - mm.w) * rsqrtf(vv.w + EPSN) * gg.w + ee.w, 0.f);
        } else {
            float din = dinv[row0 + r];
            a.x *= din; a.y *= din; a.z *= din; a.w *= din;
        }
        halfv4 hv;
        hv[0] = (half_t)a.x; hv[1] = (half_t)a.y;
        hv[2] = (half_t)a.z; hv[3] = (half_t)a.w;
        *(halfv4*)(Y + (long long)(row0 + r) * M + c4) = hv;
    }
}

// ===== CSR sum-aggregation over half rows, 8 dims/lane, unroll-2; half out =====
template <int M, int EPI>
__global__ void k_agg4h(const half_t* __restrict__ A, const int* __restrict__ rowptr,
                        const int* __restrict__ deg, const int* __restrict__ csrc,
                        const float* __restrict__ dinv,
                        const float* __restrict__ b, const float* __restrict__ g,
                        const float* __restrict__ be, const float* __restrict__ m,
                        const float* __restrict__ v,
                        half_t* __restrict__ B, int n) {
    const int LPE = M / 8;
    const int EPW = 64 / LPE;
    int node = blockIdx.x * 4 + (threadIdx.x >> 6);
    if (node >= n) return;
    int lane = threadIdx.x & 63;
    int eg = lane / LPE;
    int dl = lane % LPE;
    int beg = rowptr[node];
    int end = beg + deg[node];
    float acc[8];
#pragma unroll
    for (int j = 0; j < 8; ++j) acc[j] = 0.f;
    int i = beg + eg;
    for (; i + EPW < end; i += 2 * EPW) {
        int s0 = csrc[i];
        int s1 = csrc[i + EPW];
        halfv8 x0 = *(const halfv8*)(A + (long long)s0 * M + dl * 8);
        halfv8 x1 = *(const halfv8*)(A + (long long)s1 * M + dl * 8);
#pragma unroll
        for (int j = 0; j < 8; ++j) acc[j] += (float)x0[j] + (float)x1[j];
    }
    if (i < end) {
        int s = csrc[i];
        halfv8 xv = *(const halfv8*)(A + (long long)s * M + dl * 8);
#pragma unroll
        for (int j = 0; j < 8; ++j) acc[j] += (float)xv[j];
    }
#pragma unroll
    for (int off = LPE; off < 64; off <<= 1) {
#pragma unroll
        for (int j = 0; j < 8; ++j) acc[j] += __shfl_xor(acc[j], off);
    }
    if (eg == 0) {
        float din = dinv[node];
        int d0 = dl * 8;
        float o[8];
#pragma unroll
        for (int j = 0; j < 8; ++j) o[j] = acc[j] * din;
        if (EPI == 1) {
#pragma unroll
            for (int j = 0; j < 8; ++j) {
                int d = d0 + j;
                o[j] = fmaxf((o[j] + b[d] - m[d]) * rsqrtf(v[d] + EPSN) * g[d] + be[d], 0.f);
            }
        }
        halfv8 hw;
#pragma unroll
        for (int j = 0; j < 8; ++j) hw[j] = (half_t)o[j];
        *(halfv8*)(B + (long long)node * M + d0) = hw;
    }
}

// ===== tiny: Ws/Wd = Wg folded with ags/agd -> wsd[2][32][4] =====
__global__ void k_wsd(const float* __restrict__ Wg, const float* __restrict__ ags,
                      const float* __restrict__ agd, float* __restrict__ wsd) {
    int j = threadIdx.x;
    if (j < 128) {
        int k = j >> 2, h = j & 3;
        float ss = 0.f, dd = 0.f;
        for (int d2 = 0; d2 < 32; ++d2) {
            float wv = Wg[k * 128 + h * 32 + d2];
            ss += wv * ags[h * 32 + d2];
            dd += wv * agd[h * 32 + d2];
        }
        wsd[j] = ss;
        wsd[128 + j] = dd;
    }
}

// ===== layer-3 agg (M=32, half in) + BN/ReLU + fused attention coefs; H3 half out =====
__global__ void k_agg_att(const half_t* __restrict__ A, const int* __restrict__ rowptr,
                          const int* __restrict__ deg, const int* __restrict__ csrc,
                          const float* __restrict__ dinv,
                          const float* __restrict__ b, const float* __restrict__ g,
                          const float* __restrict__ be, const float* __restrict__ m,
                          const float* __restrict__ v, const float* __restrict__ wsd,
                          half_t* __restrict__ H3h, float* __restrict__ a_s,
                          float* __restrict__ a_d, int n) {
    __shared__ float Wl[256];
    for (int i = threadIdx.x; i < 256; i += 256) Wl[i] = wsd[i];
    __syncthreads();
    const int M = 32, EPW = 16;
    int node = blockIdx.x * 4 + (threadIdx.x >> 6);
    if (node >= n) return;
    int lane = threadIdx.x & 63;
    int eg = lane >> 2;      // 16 edge slots
    int dl = lane & 3;       // 4 lanes/row, 8 dims each
    int beg = rowptr[node];
    int end = beg + deg[node];
    float acc[8];
#pragma unroll
    for (int j = 0; j < 8; ++j) acc[j] = 0.f;
    int i = beg + eg;
    for (; i + EPW < end; i += 2 * EPW) {
        int s0 = csrc[i];
        int s1 = csrc[i + EPW];
        halfv8 x0 = *(const halfv8*)(A + (long long)s0 * M + dl * 8);
        halfv8 x1 = *(const halfv8*)(A + (long long)s1 * M + dl * 8);
#pragma unroll
        for (int j = 0; j < 8; ++j) acc[j] += (float)x0[j] + (float)x1[j];
    }
    if (i < end) {
        int s = csrc[i];
        halfv8 xv = *(const halfv8*)(A + (long long)s * M + dl * 8);
#pragma unroll
        for (int j = 0; j < 8; ++j) acc[j] += (float)xv[j];
    }
#pragma unroll
    for (int off = 4; off < 64; off <<= 1) {
#pragma unroll
        for (int j = 0; j < 8; ++j) acc[j] += __shfl_xor(acc[j], off);
    }
    float din = dinv[node];
    int d0 = dl * 8;
    float hv[8];
#pragma unroll
    for (int j = 0; j < 8; ++j) {
        int d = d0 + j;
        hv[j] = fmaxf((acc[j] * din + b[d] - m[d]) * rsqrtf(v[d] + EPSN) * g[d] + be[d], 0.f);
    }
    if (eg == 0) {
        halfv8 hw;
#pragma unroll
        for (int j = 0; j < 8; ++j) hw[j] = (half_t)hv[j];
        *(halfv8*)(H3h + (long long)node * M + d0) = hw;
    }
    // attention coefs via shfl from lanes 0..3 (dl=0..3, eg=0)
    int h = lane & 3, sel = (lane >> 2) & 1;
    const float* wp = &Wl[sel * 128];
    float o = 0.f;
#pragma unroll
    for (int src = 0; src < 4; ++src) {
#pragma unroll
        for (int j = 0; j < 8; ++j) {
            float xv = __shfl(hv[j], src);
            o += xv * wp[(src * 8 + j) * 4 + h];
        }
    }
    if (lane < 4) a_s[node * 4 + h] = o;
    else if (lane < 8) a_d[node * 4 + h] = o;
}

// ===== fused GAT: softmax + half2 gather + Wg epilogue + partial pooling =====
__global__ void k_gat4(const half_t* __restrict__ H3h, const float* __restrict__ a_s,
                       const float* __restrict__ a_d, const int* __restrict__ rowptr,
                       const int* __restrict__ deg, const int* __restrict__ csrc,
                       const float* __restrict__ Wg, const float* __restrict__ bg,
                       const int* __restrict__ batch, float* __restrict__ pooled_part,
                       int n) {
    __shared__ float sc[4][GCAP * 4];   // [w][e*4+h]
    __shared__ int   srcb[4][GCAP];
    __shared__ float wb[4][128];
    int w = threadIdx.x >> 6;
    int node = blockIdx.x * 4 + w;
    if (node >= n) return;
    int lane = threadIdx.x & 63;
    int beg = rowptr[node];
    int cnt = deg[node];
    bool fits = (cnt <= GCAP);
    float4 ad4 = ((const float4*)a_d)[node];
    float m0 = -1e30f, m1 = -1e30f, m2 = -1e30f, m3 = -1e30f;
    if (fits) {
        for (int e = lane; e < cnt; e += 64) {
            int s = csrc[beg + e];
            srcb[w][e] = s;
            float4 as = ((const float4*)a_s)[s];
            float e0 = lrelu(as.x + ad4.x);
            float e1 = lrelu(as.y + ad4.y);
            float e2 = lrelu(as.z + ad4.z);
            float e3 = lrelu(as.w + ad4.w);
            *(float4*)&sc[w][e * 4] = make_float4(e0, e1, e2, e3);
            m0 = fmaxf(m0, e0); m1 = fmaxf(m1, e1);
            m2 = fmaxf(m2, e2); m3 = fmaxf(m3, e3);
        }
    } else {
        for (int e = lane; e < cnt; e += 64) {
            int s = csrc[beg + e];
            float4 as = ((const float4*)a_s)[s];
            m0 = fmaxf(m0, lrelu(as.x + ad4.x));
            m1 = fmaxf(m1, lrelu(as.y + ad4.y));
            m2 = fmaxf(m2, lrelu(as.z + ad4.z));
            m3 = fmaxf(m3, lrelu(as.w + ad4.w));
        }
    }
#pragma unroll
    for (int o = 1; o < 64; o <<= 1) {
        m0 = fmaxf(m0, __shfl_xor(m0, o));
        m1 = fmaxf(m1, __shfl_xor(m1, o));
        m2 = fmaxf(m2, __shfl_xor(m2, o));
        m3 = fmaxf(m3, __shfl_xor(m3, o));
    }
    float s0 = 0.f, s1 = 0.f, s2 = 0.f, s3 = 0.f;
    if (fits) {
        for (int e = lane; e < cnt; e += 64) {
            float4 sv = *(float4*)&sc[w][e * 4];
            float p0 = __expf(sv.x - m0);
            float p1 = __expf(sv.y - m1);
            float p2 = __expf(sv.z - m2);
            float p3 = __expf(sv.w - m3);
            *(float4*)&sc[w][e * 4] = make_float4(p0, p1, p2, p3);
            s0 += p0; s1 += p1; s2 += p2; s3 += p3;
        }
    } else {
        for (int e = lane; e < cnt; e += 64) {
            int s = csrc[beg + e];
            float4 as = ((const float4*)a_s)[s];
            s0 += __expf(lrelu(as.x + ad4.x) - m0);
            s1 += __expf(lrelu(as.y + ad4.y) - m1);
            s2 += __expf(lrelu(as.z + ad4.z) - m2);
            s3 += __expf(lrelu(as.w + ad4.w) - m3);
        }
    }
#pragma unroll
    for (int o = 1; o < 64; o <<= 1) {
        s0 += __shfl_xor(s0, o);
        s1 += __shfl_xor(s1, o);
        s2 += __shfl_xor(s2, o);
        s3 += __shfl_xor(s3, o);
    }
    float inv0 = 0.25f / s0, inv1 = 0.25f / s1, inv2 = 0.25f / s2, inv3 = 0.25f / s3;
    // phase 2: quarter-wave per edge; lane -> q=lane>>4, k=lane&15 (dims 2k,2k+1)
    int q = lane >> 4;
    int k = lane & 15;
    float acc[8];
#pragma unroll
    for (int j = 0; j < 8; ++j) acc[j] = 0.f;
    if (fits) {
        int i = q;
        for (; i + 4 < cnt; i += 8) {
            int sA = srcb[w][i];
            int sB = srcb[w][i + 4];
            halfv2 xA = *(const halfv2*)(H3h + (long long)sA * 32 + 2 * k);
            halfv2 xB = *(const halfv2*)(H3h + (long long)sB * 32 + 2 * k);
            float4 wA = *(float4*)&sc[w][i * 4];
            float4 wB = *(float4*)&sc[w][(i + 4) * 4];
            float a0 = (float)xA[0], a1 = (float)xA[1];
            float b0 = (float)xB[0], b1 = (float)xB[1];
            acc[0] += wA.x * a0 + wB.x * b0; acc[1] += wA.x * a1 + wB.x * b1;
            acc[2] += wA.y * a0 + wB.y * b0; acc[3] += wA.y * a1 + wB.y * b1;
            acc[4] += wA.z * a0 + wB.z * b0; acc[5] += wA.z * a1 + wB.z * b1;
            acc[6] += wA.w * a0 + wB.w * b0; acc[7] += wA.w * a1 + wB.w * b1;
        }
        if (i < cnt) {
            int s = srcb[w][i];
            halfv2 xv = *(const halfv2*)(H3h + (long long)s * 32 + 2 * k);
            float4 wv = *(float4*)&sc[w][i * 4];
            float x0 = (float)xv[0], x1 = (float)xv[1];
            acc[0] += wv.x * x0; acc[1] += wv.x * x1;
            acc[2] += wv.y * x0; acc[3] += wv.y * x1;
            acc[4] += wv.z * x0; acc[5] += wv.z * x1;
            acc[6] += wv.w * x0; acc[7] += wv.w * x1;
        }
    } else {
        for (int i = q; i < cnt; i += 4) {
            int s = csrc[beg + i];
            float4 as = ((const float4*)a_s)[s];
            float p0 = __expf(lrelu(as.x + ad4.x) - m0);
            float p1 = __expf(lrelu(as.y + ad4.y) - m1);
            float p2 = __expf(lrelu(as.z + ad4.z) - m2);
            float p3 = __expf(lrelu(as.w + ad4.w) - m3);
            halfv2 xv = *(const halfv2*)(H3h + (long long)s * 32 + 2 * k);
            float x0 = (float)xv[0], x1 = (float)xv[1];
            acc[0] += p0 * x0; acc[1] += p0 * x1;
            acc[2] += p1 * x0; acc[3] += p1 * x1;
            acc[4] += p2 * x0; acc[5] += p2 * x1;
            acc[6] += p3 * x0; acc[7] += p3 * x1;
        }
    }
#pragma unroll
    for (int o = 16; o < 64; o <<= 1) {
#pragma unroll
        for (int j = 0; j < 8; ++j) acc[j] += __shfl_xor(acc[j], o);
    }
    if (q == 0) {
        float invh[4] = {inv0, inv1, inv2, inv3};
#pragma unroll
        for (int h = 0; h < 4; ++h) {
            wb[w][h * 32 + 2 * k]     = acc[h * 2]     * invh[h];
            wb[w][h * 32 + 2 * k + 1] = acc[h * 2 + 1] * invh[h];
        }
    }
    // epilogue + partial pooling (no H4 materialization)
    int d = lane & 31;
    int h0 = lane >> 5;
    int half_ = h0 * 64;
    float o = 0.f;
#pragma unroll
    for (int j = 0; j < 64; ++j) {
        int jj = half_ + j;
        o += wb[w][jj] * Wg[(jj & 31) * 128 + (jj >> 5) * 32 + d];
    }
    o += __shfl_xor(o, 32);
    if (lane < 32) {
        float val = fmaxf(o + bg[d], 0.f);
        int g = batch[node];
        float* pp = pooled_part + (size_t)(blockIdx.x & (NPART - 1)) * PSTR;
        atomicAdd(&pp[g * 32 + d], val);
        if (d == 0) atomicAdd(&pp[NGRAPH * 32 + g], 1.f);
    }
}

// ===================== pool reduce (partials -> pooled+cnt) =====================
__global__ void k_pool_reduce(const float* __restrict__ part, float* __restrict__ outp) {
    int i = blockIdx.x * blockDim.x + threadIdx.x;
    if (i >= PSTR) return;
    float s = 0.f;
#pragma unroll 8
    for (int c = 0; c < NPART; ++c) s += part[(size_t)c * PSTR + i];
    outp[i] = s;
}

// ===================== classifier =====================
__global__ void k_classifier(const float* __restrict__ pooled, const float* __restrict__ cnt,
                             const float* __restrict__ Wc1, const float* __restrict__ bc1,
                             const float* __restrict__ Wc2, const float* __restrict__ bc2,
                             float* __restrict__ out) {
    __shared__ float pl[NGRAPH * 32];
    __shared__ float t1[NGRAPH * 16];
    int tid = threadIdx.x;
    for (int i = tid; i < NGRAPH * 32; i += blockDim.x) {
        int g = i >> 5;
        pl[i] = pooled[i] / fmaxf(cnt[g], 1.f);
    }
    __syncthreads();
    for (int i = tid; i < NGRAPH * 16; i += blockDim.x) {
        int g = i >> 4, c = i & 15;
        float acc = bc1[c];
#pragma unroll
        for (int d = 0; d < 32; ++d) acc += pl[g * 32 + d] * Wc1[d * 16 + c];
        t1[i] = fmaxf(acc, 0.f);
    }
    __syncthreads();
    for (int i = tid; i < NGRAPH * 5; i += blockDim.x) {
        int g = i / 5, c = i % 5;
        float acc = bc2[c];
#pragma unroll
        for (int k = 0; k < 16; ++k) acc += t1[g * 16 + k] * Wc2[k * 5 + c];
        out[i] = acc;
    }
}

// ===================== launch =====================
static inline dim3 gsz(long long work, int block = 256) {
    long long g = (work + block - 1) / block;
    if (g > 262144) g = 262144;
    if (g < 1) g = 1;
    return dim3((unsigned)g);
}

extern "C" void kernel_launch(void* const* d_in, const int* in_sizes, int n_in,
                              void* d_out, int out_size, void* d_ws, size_t ws_size,
                              hipStream_t stream) {
    const float* x     = (const float*)d_in[0];
    const int*   ei    = (const int*)d_in[1];
    const int*   batch = (const int*)d_in[2];
    const float* W1 = (const float*)d_in[3];  const float* b1 = (const float*)d_in[4];
    const float* W2 = (const float*)d_in[5];  const float* b2 = (const float*)d_in[6];
    const float* W3 = (const float*)d_in[7];  const float* b3 = (const float*)d_in[8];
    const float* g1 = (const float*)d_in[9];  const float* be1 = (const float*)d_in[10];
    const float* m1 = (const float*)d_in[11]; const float* v1  = (const float*)d_in[12];
    const float* g2 = (const float*)d_in[13]; const float* be2 = (const float*)d_in[14];
    const float* m2 = (const float*)d_in[15]; const float* v2  = (const float*)d_in[16];
    const float* g3 = (const float*)d_in[17]; const float* be3 = (const float*)d_in[18];
    const float* m3 = (const float*)d_in[19]; const float* v3  = (const float*)d_in[20];
    const float* Wg  = (const float*)d_in[21];
    const float* ags = (const float*)d_in[22];
    const float* agd = (const float*)d_in[23];
    const float* bg  = (const float*)d_in[24];
    const float* Wc1 = (const float*)d_in[25]; const float* bc1 = (const float*)d_in[26];
    const float* Wc2 = (const float*)d_in[27]; const float* bc2 = (const float*)d_in[28];
    float* out = (float*)d_out;

    const int N = in_sizes[0] / 64;
    const int E = in_sizes[1] / 2;
    const int* esrc = ei;
    const int* edst = ei + E;
    const int NB = (N + NPBK - 1) >> BSHIFT;

    size_t off = 0;
    auto take = [&](size_t bytes) -> void* {
        void* p = (char*)d_ws + off;
        off += bytes;
        off = (off + 255) & ~(size_t)255;
        return p;
    };
    int*    deg    = (int*)take((size_t)N * 4);
    float*  dinv   = (float*)take((size_t)N * 4);
    int*    rowptr = (int*)take((size_t)N * 4);
    int*    bsize  = (int*)take((size_t)1024 * 4);
    int*    bbase  = (int*)take((size_t)1024 * 4);
    int*    gcur   = (int*)take((size_t)1024 * 4);
    float*  wsd    = (float*)take((size_t)256 * 4);
    int*    csrc   = (int*)take((size_t)(E + N) * 4);
    half_t* bufAh  = (half_t*)take((size_t)N * 64 * 2);  // xh -> A2h -> A3h
    half_t* bufBh  = (half_t*)take((size_t)N * 64 * 2);  // Xa -> H2
    float*  bufC   = (float*)take((size_t)N * 128 * 4);  // binned(u32,E) ; H1h (half,N*128)
    half_t* h3h    = (half_t*)take((size_t)N * 32 * 2);
    float*  a_s    = (float*)take((size_t)N * 4 * 4);
    float*  a_d    = (float*)take((size_t)N * 4 * 4);
    float*  ppart  = (float*)take((size_t)NPART * PSTR * 4);
    float*  pooled = (float*)take((size_t)PSTR * 4);
    float*  cnt    = pooled + NGRAPH * 32;
    unsigned* binned = (unsigned*)bufC;
    half_t* H1h    = (half_t*)bufC;                      // binned dead before H1 written
    (void)ws_size; (void)n_in; (void)out_size;

    const dim3 B256(256);

    // ---- binned CSR build ----
    hipMemsetAsync(bsize, 0, (size_t)NB * 4, stream);
    hipMemsetAsync(ppart, 0, (size_t)NPART * PSTR * 4, stream);
    hipLaunchKernelGGL(k_bin_count, dim3(512), B256, 0, stream, edst, bsize, E, NB);
    hipLaunchKernelGGL(k_bucket_scan, dim3(1), dim3(64), 0, stream, bsize, bbase, gcur, NB);
    hipLaunchKernelGGL(k_bin_write, dim3(512), B256, 0, stream, esrc, edst, gcur, binned, E, NB);
    hipLaunchKernelGGL(k_csr_build, dim3(NB), B256, 0, stream,
                       binned, bbase, bsize, rowptr, deg, dinv, csrc, N);
    hipLaunchKernelGGL(k_wsd, dim3(1), dim3(128), 0, stream, Wg, ags, agd, wsd);

    // ---- layer 1: xh = half(x*dinv); Xa = half(dinv*sum(xh)); H1h = half(relu(BN(Xa@W1+b1)))
    hipLaunchKernelGGL(k_cvt_xh, gsz((long long)N * 8), B256, 0, stream, x, dinv, bufAh, N);
    hipLaunchKernelGGL((k_agg4h<64, 0>), dim3((N + 3) / 4), B256, 0, stream,
                       bufAh, rowptr, deg, csrc, dinv,
                       nullptr, nullptr, nullptr, nullptr, nullptr, bufBh, N);
    hipLaunchKernelGGL((k_matmulh<64, 128, 1>), dim3((N + 31) / 32), B256, 0, stream,
                       bufBh, W1, H1h, N, b1, g1, be1, m1, v1, nullptr);
    // ---- layer 2: A2h = half((H1@W2)*dinv); H2 = half(relu(BN(dinv*sum(A2h)+b2)))
    hipLaunchKernelGGL((k_matmulh<128, 64, 2>), dim3((N + 63) / 64), B256, 0, stream,
                       H1h, W2, bufAh, N, nullptr, nullptr, nullptr, nullptr, nullptr, dinv);
    hipLaunchKernelGGL((k_agg4h<64, 1>), dim3((N + 3) / 4), B256, 0, stream,
                       bufAh, rowptr, deg, csrc, dinv, b2, g2, be2, m2, v2, bufBh, N);
    // ---- layer 3: A3h = half((H2@W3)*dinv); H3h + a_s/a_d fused
    hipLaunchKernelGGL((k_matmulh<64, 32, 2>), dim3((N + 127) / 128), B256, 0, stream,
                       bufBh, W3, bufAh, N, nullptr, nullptr, nullptr, nullptr, nullptr, dinv);
    hipLaunchKernelGGL(k_agg_att, dim3((N + 3) / 4), B256, 0, stream,
                       bufAh, rowptr, deg, csrc, dinv, b3, g3, be3, m3, v3,
                       wsd, h3h, a_s, a_d, N);

    // ---- GAT (half H3 gather; pooling fused via partials, no H4)
    hipLaunchKernelGGL(k_gat4, dim3((N + 3) / 4), B256, 0, stream,
                       h3h, a_s, a_d, rowptr, deg, csrc, Wg, bg, batch, ppart, N);

    // ---- pool reduce + classifier
    hipLaunchKernelGGL(k_pool_reduce, dim3((PSTR + 255) / 256), B256, 0, stream, ppart, pooled);
    hipLaunchKernelGGL(k_classifier, dim3(1), B256, 0, stream, pooled, cnt, Wc1, bc1, Wc2, bc2, out);
}